// Round 1
// baseline (695.107 us; speedup 1.0000x reference)
//
#include <hip/hip_runtime.h>

#define NCLS 62
#define HW (512 * 512)
#define NHW (8 * 512 * 512)
#define CHW (NCLS * HW)
#define IGNORE_INDEX 255
#define SMOOTH 1e-6f

// ---------------------------------------------------------------------------
// Kernel 0: zero the 3*64-float accumulator region of the workspace
// (harness poisons d_ws with 0xAA before every timed launch).
// ---------------------------------------------------------------------------
__global__ void zero_ws_kernel(float* ws) {
    ws[threadIdx.x] = 0.0f;   // 192 threads cover ps[64] | inter[64] | tgt[64]
}

// ---------------------------------------------------------------------------
// Kernel 1: streaming softmax + per-class partial reductions.
// One pixel per thread per grid-stride iteration. For fixed class c the wave's
// 64 lanes read 64 consecutive floats -> coalesced. 62 independent loads per
// pixel provide the MLP to hide HBM latency at 2 waves/SIMD.
// ---------------------------------------------------------------------------
__global__ __launch_bounds__(256, 2)
void dice_main_kernel(const float* __restrict__ pred,
                      const int* __restrict__ target,
                      float* __restrict__ g_ps,
                      float* __restrict__ g_inter,
                      float* __restrict__ g_tgt) {
    // s_acc[c][lane]: per-lane-column accumulation of pred_sums across the
    // block's 4 waves (LDS atomic, 4-way max contention, 2-way bank alias =
    // free). Padded to 65 so the final column-sum (lane c reads row c) is
    // conflict-free: bank = (c*65 + i) % 32 varies with c.
    __shared__ float s_acc[NCLS][65];
    __shared__ float s_inter[NCLS];
    __shared__ float s_tgt[NCLS];

    const int tid  = threadIdx.x;
    const int lane = tid & 63;

    for (int i = tid; i < NCLS * 65; i += 256) ((float*)s_acc)[i] = 0.0f;
    if (tid < NCLS) { s_inter[tid] = 0.0f; s_tgt[tid] = 0.0f; }
    __syncthreads();

    float acc[NCLS];
#pragma unroll
    for (int c = 0; c < NCLS; ++c) acc[c] = 0.0f;

    const int stride = gridDim.x * 256;
    for (int p = blockIdx.x * 256 + tid; p < NHW; p += stride) {
        const int n   = p >> 18;            // HW = 2^18
        const int rem = p & (HW - 1);
        const float* bp = pred + (size_t)n * CHW + rem;

        // Load all 62 class logits for this pixel (independent loads).
        float e[NCLS];
#pragma unroll
        for (int c = 0; c < NCLS; ++c) e[c] = bp[(size_t)c * HW];

        const int t = target[p];
        const bool valid = (t != IGNORE_INDEX);

        // exp + denominator + gather-at-target (cndmask select: no runtime
        // register indexing, which would spill the array to scratch).
        float s = 0.0f, gath = 0.0f;
#pragma unroll
        for (int c = 0; c < NCLS; ++c) {
            const float ex = __expf(e[c]);
            e[c] = ex;
            s += ex;
            gath = (c == t) ? ex : gath;
        }

        const float inv = valid ? (1.0f / s) : 0.0f;  // validf mask folded in
#pragma unroll
        for (int c = 0; c < NCLS; ++c) acc[c] += e[c] * inv;

        if (valid) {
            atomicAdd(&s_inter[t], gath * inv);
            atomicAdd(&s_tgt[t], 1.0f);
        }
    }

    // Block-level reduction of per-thread acc[] via lane columns.
#pragma unroll
    for (int c = 0; c < NCLS; ++c) atomicAdd(&s_acc[c][lane], acc[c]);
    __syncthreads();

    if (tid < NCLS) {
        float tot = 0.0f;
#pragma unroll 8
        for (int l = 0; l < 64; ++l) tot += s_acc[tid][l];
        atomicAdd(&g_ps[tid], tot);
        atomicAdd(&g_inter[tid], s_inter[tid]);
        atomicAdd(&g_tgt[tid], s_tgt[tid]);
    }
}

// ---------------------------------------------------------------------------
// Kernel 2: dice epilogue over 62 classes, one wave.
// ---------------------------------------------------------------------------
__global__ void dice_final_kernel(const float* __restrict__ g_ps,
                                  const float* __restrict__ g_inter,
                                  const float* __restrict__ g_tgt,
                                  float* __restrict__ out) {
    const int c = threadIdx.x;
    float dice = 0.0f, has = 0.0f;
    if (c < NCLS) {
        const float un = g_ps[c] + g_tgt[c];
        if (un > 0.0f) {
            has  = 1.0f;
            dice = (2.0f * g_inter[c] + SMOOTH) / (un + SMOOTH);
        }
    }
#pragma unroll
    for (int off = 32; off; off >>= 1) {
        dice += __shfl_down(dice, off);
        has  += __shfl_down(has, off);
    }
    if (c == 0) {
        const float mean = (has > 0.0f) ? (dice / fmaxf(has, 1.0f)) : 1.0f;
        out[0] = 1.0f - mean;
    }
}

extern "C" void kernel_launch(void* const* d_in, const int* in_sizes, int n_in,
                              void* d_out, int out_size, void* d_ws, size_t ws_size,
                              hipStream_t stream) {
    const float* pred   = (const float*)d_in[0];
    const int*   target = (const int*)d_in[1];
    float* ws      = (float*)d_ws;
    float* g_ps    = ws;
    float* g_inter = ws + 64;
    float* g_tgt   = ws + 128;
    float* out     = (float*)d_out;

    zero_ws_kernel<<<1, 192, 0, stream>>>(ws);
    // 512 blocks * 256 threads = 131072 threads, 16 pixels each (NHW = 2^21).
    dice_main_kernel<<<512, 256, 0, stream>>>(pred, target, g_ps, g_inter, g_tgt);
    dice_final_kernel<<<1, 64, 0, stream>>>(g_ps, g_inter, g_tgt, out);
}